// Round 5
// baseline (1515.424 us; speedup 1.0000x reference)
//
#include <hip/hip_runtime.h>

#define Hd 256
#define Wd 256
#define HW 65536
#define C 64
#define B 8
#define M 16
#define NDEPTH 4
#define NMLP 128

// ---------------- twiddle table: e^{2*pi*i*t/256}, double-precision accurate --------------
__global__ void k_table(float2* __restrict__ tab) {
    int t = threadIdx.x;
    double a = (6.283185307179586476925286766559 / 256.0) * (double)t;
    tab[t] = make_float2((float)cos(a), (float)sin(a));
}

// ---------------- fc0: 3 -> 64 channels, per pixel ----------------
__global__ void k_fc0(const float* __restrict__ x, const float* __restrict__ w,
                      const float* __restrict__ bias, float* __restrict__ h) {
    int p = blockIdx.x * 256 + threadIdx.x;   // 0 .. B*HW-1
    int b = p >> 16, pix = p & 65535;
    float x0 = x[(b * 3 + 0) * HW + pix];
    float x1 = x[(b * 3 + 1) * HW + pix];
    float x2 = x[(b * 3 + 2) * HW + pix];
    for (int o = 0; o < C; ++o) {
        float v = bias[o];
        v = fmaf(w[o * 3 + 0], x0, v);
        v = fmaf(w[o * 3 + 1], x1, v);
        v = fmaf(w[o * 3 + 2], x2, v);
        h[(b * C + o) * HW + pix] = v;
    }
}

// ---------------- forward DFT along y: T1[bc,ky,w] = sum_y h[bc,y,w] e^{-2pi i ky y/256} ---
// R5: tab via LDS (broadcast ds_read) — scalar s_load of tab in the loop mixed SMEM+DS
// wait semantics (SMEM is out-of-order -> lgkmcnt(0) drains per iteration).
__global__ __launch_bounds__(256, 2)
void k_fwd_y(const float* __restrict__ h, const float2* __restrict__ tab,
             float2* __restrict__ T1) {
    __shared__ float2 st[256];
    int bc = blockIdx.x;          // b*C+c
    int w = threadIdx.x;          // 0..255
    st[w] = tab[w];
    __syncthreads();
    const float* hp = h + bc * HW + w;
    float ar[M], ai[M];
#pragma unroll
    for (int k = 0; k < M; ++k) { ar[k] = 0.f; ai[k] = 0.f; }
    for (int y = 0; y < Hd; ++y) {
        float v = hp[y * Wd];
#pragma unroll
        for (int k = 0; k < M; ++k) {
            float2 e = st[(k * y) & 255];    // uniform LDS broadcast, in-order
            ar[k] = fmaf(v, e.x, ar[k]);
            ai[k] = fmaf(v, -e.y, ai[k]);
        }
    }
    float2* out = T1 + bc * (M * Wd) + w;
#pragma unroll
    for (int k = 0; k < M; ++k) out[k * Wd] = make_float2(ar[k], ai[k]);
}

// ---------------- forward DFT along x: X[bc, ky*16+kx] = sum_w T1[bc,ky,w] e^{-2pi i kx w/256}
__global__ __launch_bounds__(256, 2)
void k_fwd_x(const float2* __restrict__ T1, const float2* __restrict__ tab,
             float2* __restrict__ X) {
    __shared__ float2 sT[M * Wd];   // 32 KB
    __shared__ float2 st[256];      // 2 KB
    int bc = blockIdx.x, t = threadIdx.x;
    const float2* src = T1 + bc * (M * Wd);
#pragma unroll
    for (int j = 0; j < M; ++j) sT[j * 256 + t] = src[j * 256 + t];
    st[t] = tab[t];
    __syncthreads();
    int ky = t >> 4, kx = t & 15;
    // 2 independent chains (w even / w odd)
    float xr0 = 0.f, xi0 = 0.f, xr1 = 0.f, xi1 = 0.f;
    for (int w = 0; w < Wd; w += 2) {
        float2 Ta = sT[ky * 256 + w];
        float2 ea = st[(kx * w) & 255];
        xr0 = fmaf(Ta.x, ea.x, fmaf(Ta.y, ea.y, xr0));
        xi0 = fmaf(Ta.y, ea.x, fmaf(-Ta.x, ea.y, xi0));
        float2 Tb = sT[ky * 256 + w + 1];
        float2 eb = st[(kx * (w + 1)) & 255];
        xr1 = fmaf(Tb.x, eb.x, fmaf(Tb.y, eb.y, xr1));
        xi1 = fmaf(Tb.y, eb.x, fmaf(-Tb.x, eb.y, xi1));
    }
    X[bc * 256 + t] = make_float2(xr0 + xr1, xi0 + xi1);
}

// ---------------- mode mixing: Y[b,o,m] = sum_i X[b,i,m] * (wre+j*wim)[i,o,m] -------------
// Loop loads are all coalesced GLOBAL (vmcnt, fine-grained) — leave as-is.
__global__ __launch_bounds__(256, 2)
void k_mix(const float2* __restrict__ X, const float* __restrict__ wre,
           const float* __restrict__ wim, float2* __restrict__ Y) {
    int o = blockIdx.x >> 2;   // 0..63
    int bq = blockIdx.x & 3;   // pair of batches
    int m = threadIdx.x;       // mode = ky*16+kx
    int b0 = bq * 2, b1 = bq * 2 + 1;
    float yr0 = 0.f, yi0 = 0.f, yr1 = 0.f, yi1 = 0.f;
    for (int i = 0; i < C; ++i) {
        float wr = wre[(i * C + o) * 256 + m];
        float wi = wim[(i * C + o) * 256 + m];
        float2 x0 = X[(b0 * C + i) * 256 + m];
        float2 x1 = X[(b1 * C + i) * 256 + m];
        yr0 = fmaf(x0.x, wr, fmaf(-x0.y, wi, yr0));
        yi0 = fmaf(x0.x, wi, fmaf(x0.y, wr, yi0));
        yr1 = fmaf(x1.x, wr, fmaf(-x1.y, wi, yr1));
        yi1 = fmaf(x1.x, wi, fmaf(x1.y, wr, yi1));
    }
    Y[(b0 * C + o) * 256 + m] = make_float2(yr0, yi0);
    Y[(b1 * C + o) * 256 + m] = make_float2(yr1, yi1);
}

// ---------------- inverse along y (with 1/(H*W) and Hermitian x2 folded in) ---------------
// G[bc, y, kx] = scale(kx) * sum_ky Y[bc, ky*16+kx] e^{+2pi i ky y/256}
__global__ __launch_bounds__(256, 2)
void k_inv_y(const float2* __restrict__ Y, const float2* __restrict__ tab,
             float2* __restrict__ G) {
    __shared__ float2 sY[256];
    __shared__ float2 st[256];
    int bc = blockIdx.x, t = threadIdx.x;   // t = y
    sY[t] = Y[bc * 256 + t];
    st[t] = tab[t];
    __syncthreads();
    float2 out[M];
#pragma unroll
    for (int kx = 0; kx < M; ++kx) {
        float gr = 0.f, gi = 0.f;
#pragma unroll
        for (int ky = 0; ky < M; ++ky) {
            float2 yv = sY[ky * 16 + kx];
            float2 e = st[(ky * t) & 255];
            gr = fmaf(yv.x, e.x, fmaf(-yv.y, e.y, gr));
            gi = fmaf(yv.x, e.y, fmaf(yv.y, e.x, gi));
        }
        float sc = (kx == 0 ? 1.0f : 2.0f) * (1.0f / 65536.0f);
        out[kx] = make_float2(gr * sc, gi * sc);
    }
    float2* gp = G + (bc * 256 + t) * M;
#pragma unroll
    for (int kx = 0; kx < M; ++kx) gp[kx] = out[kx];
}

// ---------------- fused: inverse along x + conv1x1 + add + relu, in-place on h ------------
// R1: (256,2) kills hp[64] spill. R3: sG in LDS. R4 post-mortem: per-o s_loads of ww mixed
// with ds_reads force lgkmcnt(0) every iteration (SMEM returns out-of-order) -> ~50% stall.
// R5: ww/wb ALSO staged in LDS -> hot loop is pure DS (in-order, compiler emits fine-grained
// lgkmcnt(N)) + VALU. All loop LDS reads are wave-uniform broadcasts (conflict-free).
__global__ __launch_bounds__(256, 2)
void k_final(float* __restrict__ h, const float2* __restrict__ G,
             const float* __restrict__ ww, const float* __restrict__ wb,
             const float2* __restrict__ tab) {
    __shared__ float4 sW[C * 16];   // 16 KB: ww[o][i] as 16 float4 per o
    __shared__ float2 sG[C * M];    // 8 KB, [o][k]
    __shared__ float2 st[256];      // 2 KB
    __shared__ float  sB[C];        // 256 B
    int by = blockIdx.x;
    int b = by >> 8, y = by & 255;
    int x = threadIdx.x;
    st[x] = tab[x];
    {   // stage ww: 1024 float4, coalesced
        const float4* wf4 = (const float4*)ww;
#pragma unroll
        for (int p = 0; p < 4; ++p) sW[x + p * 256] = wf4[x + p * 256];
    }
    if (x < C) sB[x] = wb[x];
    {   // stage G slice: 512 float4; threads f=8o..8o+7 fetch one 128 B row (coalesced)
        const float4* Gf4 = (const float4*)G;
        float4* sGf4 = (float4*)sG;
        int f0 = x, o0 = f0 >> 3, q0 = f0 & 7;
        sGf4[f0] = Gf4[((size_t)(b * C + o0) * 256 + y) * 8 + q0];
        int f1 = x + 256, o1 = f1 >> 3, q1 = f1 & 7;
        sGf4[f1] = Gf4[((size_t)(b * C + o1) * 256 + y) * 8 + q1];
    }
    __syncthreads();
    float cs[M], sn[M];
#pragma unroll
    for (int k = 0; k < M; ++k) {
        float2 e = st[(k * x) & 255];
        cs[k] = e.x; sn[k] = e.y;
    }
    float hp[C];
    float* hb = h + b * C * HW + y * Wd + x;
#pragma unroll
    for (int i = 0; i < C; ++i) hp[i] = hb[i * HW];
    const float4* sG4 = (const float4*)sG;
    for (int o = 0; o < C; ++o) {
        float a0 = sB[o], a1 = 0.f, a2 = 0.f, a3 = 0.f;
#pragma unroll
        for (int c = 0; c < 16; ++c) {
            float4 wv = sW[o * 16 + c];      // broadcast ds_read_b128, in-order
            a0 = fmaf(wv.x, hp[4 * c + 0], a0);
            a1 = fmaf(wv.y, hp[4 * c + 1], a1);
            a2 = fmaf(wv.z, hp[4 * c + 2], a2);
            a3 = fmaf(wv.w, hp[4 * c + 3], a3);
        }
#pragma unroll
        for (int q = 0; q < 8; ++q) {
            float4 g = sG4[o * 8 + q];       // (re,im,re,im) for k=2q,2q+1
            a0 = fmaf(g.x, cs[2 * q], a0);
            a1 = fmaf(-g.y, sn[2 * q], a1);
            a2 = fmaf(g.z, cs[2 * q + 1], a2);
            a3 = fmaf(-g.w, sn[2 * q + 1], a3);
        }
        hb[o * HW] = fmaxf((a0 + a1) + (a2 + a3), 0.0f);
    }
}

// ---------------- fused fc1 (relu) + fc2, per pixel ----------------
// R5: w1 (32 KB), b1, w2 staged in LDS -> pure-DS hot loop (was SMEM per m, with
// 32 KB working set likely thrashing the scalar cache on top of the lgkmcnt(0) drain).
__global__ __launch_bounds__(256, 2)
void k_fc12(const float* __restrict__ h, const float* __restrict__ w1,
            const float* __restrict__ b1, const float* __restrict__ w2,
            const float* __restrict__ b2, float* __restrict__ out) {
    __shared__ float4 sW1[NMLP * 16];   // 32 KB
    __shared__ float  sB1[NMLP];        // 512 B
    __shared__ float  sW2[3 * NMLP];    // 1.5 KB
    int by = blockIdx.x;
    int b = by >> 8, y = by & 255;
    int x = threadIdx.x;
    {   // stage w1: 2048 float4, coalesced
        const float4* wf4 = (const float4*)w1;
#pragma unroll
        for (int p = 0; p < 8; ++p) sW1[x + p * 256] = wf4[x + p * 256];
    }
    if (x < NMLP) sB1[x] = b1[x];
    sW2[x] = w2[x];                     // covers 0..255
    if (x < 3 * NMLP - 256) sW2[256 + x] = w2[256 + x];
    __syncthreads();
    const float* hb = h + b * C * HW + y * Wd + x;
    float hp[C];
#pragma unroll
    for (int i = 0; i < C; ++i) hp[i] = hb[i * HW];
    float a0 = b2[0], a1 = b2[1], a2 = b2[2];
    for (int m = 0; m < NMLP; ++m) {
        float c0 = sB1[m], c1 = 0.f, c2 = 0.f, c3 = 0.f;
#pragma unroll
        for (int c = 0; c < 16; ++c) {
            float4 wv = sW1[m * 16 + c];    // broadcast ds_read_b128
            c0 = fmaf(wv.x, hp[4 * c + 0], c0);
            c1 = fmaf(wv.y, hp[4 * c + 1], c1);
            c2 = fmaf(wv.z, hp[4 * c + 2], c2);
            c3 = fmaf(wv.w, hp[4 * c + 3], c3);
        }
        float acc = fmaxf((c0 + c1) + (c2 + c3), 0.0f);
        a0 = fmaf(sW2[0 * NMLP + m], acc, a0);
        a1 = fmaf(sW2[1 * NMLP + m], acc, a1);
        a2 = fmaf(sW2[2 * NMLP + m], acc, a2);
    }
    float* ob = out + b * 3 * HW + y * Wd + x;
    ob[0] = a0;
    ob[HW] = a1;
    ob[2 * HW] = a2;
}

extern "C" void kernel_launch(void* const* d_in, const int* in_sizes, int n_in,
                              void* d_out, int out_size, void* d_ws, size_t ws_size,
                              hipStream_t stream) {
    const float* x     = (const float*)d_in[0];
    const float* fc0_w = (const float*)d_in[1];
    const float* fc0_b = (const float*)d_in[2];
    const float* swre  = (const float*)d_in[3];   // [4,64,64,16,16]
    const float* swim  = (const float*)d_in[4];
    const float* ww    = (const float*)d_in[5];   // [4,64,64]
    const float* wb    = (const float*)d_in[6];   // [4,64]
    const float* fc1w  = (const float*)d_in[7];
    const float* fc1b  = (const float*)d_in[8];
    const float* fc2w  = (const float*)d_in[9];
    const float* fc2b  = (const float*)d_in[10];

    float* ws = (float*)d_ws;
    float2* tab = (float2*)ws;                               // 512 floats
    float*  h   = ws + 512;                                  // 33,554,432 floats
    float2* T1  = (float2*)(ws + 512 + 33554432);            // 4,194,304 floats (doubles as G)
    float2* X   = (float2*)(ws + 512 + 33554432 + 4194304);  // 262,144 floats
    float2* Y   = (float2*)(ws + 512 + 33554432 + 4194304 + 262144); // 262,144 floats
    // total ~153 MB of workspace

    k_table<<<dim3(1), dim3(256), 0, stream>>>(tab);
    k_fc0<<<dim3(2048), dim3(256), 0, stream>>>(x, fc0_w, fc0_b, h);

    for (int d = 0; d < NDEPTH; ++d) {
        k_fwd_y<<<dim3(512), dim3(256), 0, stream>>>(h, tab, T1);
        k_fwd_x<<<dim3(512), dim3(256), 0, stream>>>(T1, tab, X);
        k_mix<<<dim3(256), dim3(256), 0, stream>>>(X, swre + (size_t)d * C * C * 256,
                                                   swim + (size_t)d * C * C * 256, Y);
        k_inv_y<<<dim3(512), dim3(256), 0, stream>>>(Y, tab, T1 /* reused as G */);
        k_final<<<dim3(2048), dim3(256), 0, stream>>>(h, T1, ww + d * C * C, wb + d * C, tab);
    }
    k_fc12<<<dim3(2048), dim3(256), 0, stream>>>(h, fc1w, fc1b, fc2w, fc2b, (float*)d_out);
}